// Round 4
// baseline (541.653 us; speedup 1.0000x reference)
//
#include <hip/hip_runtime.h>

#define SPAT 32768   // 32*32*32
#define BATCH 2
#define GN_EPS 1e-5f

// =====================================================================
// 1x1x1 conv, LDS-position-tile template: read input ONCE, write ONCE.
// Block 256 thr = 4 waves; tile = 64 positions; wave w computes outputs
// [w*8, w*8+8) for COUT=32. Weights are wave-uniform -> s_load.
// grid: (SPAT/64, 1, B)
// =====================================================================
template <int CIN, bool RELU>
__global__ __launch_bounds__(256) void k_c1t(
    const float* __restrict__ in, const float* __restrict__ w,
    const float* __restrict__ sc, const float* __restrict__ bi,
    float* __restrict__ out)
{
    __shared__ float lds[CIN * 64];
    int spos = blockIdx.x * 64, b = blockIdx.z;
    const float* ip = in + (size_t)b * CIN * SPAT + spos;
    for (int i = threadIdx.x; i < CIN * 16; i += 256) {
        int c = i >> 4, p4 = (i & 15) << 2;
        *(float4*)&lds[c * 64 + p4] = *(const float4*)(ip + (size_t)c * SPAT + p4);
    }
    __syncthreads();
    int pos = threadIdx.x & 63, wv = threadIdx.x >> 6;
    int o0 = wv * 8;
    float acc[8];
#pragma unroll
    for (int j = 0; j < 8; ++j) acc[j] = 0.f;
#pragma unroll 4
    for (int c = 0; c < CIN; ++c) {
        float v = lds[c * 64 + pos];
#pragma unroll
        for (int j = 0; j < 8; ++j)
            acc[j] = fmaf(v, w[(o0 + j) * CIN + c], acc[j]);
    }
#pragma unroll
    for (int j = 0; j < 8; ++j) {
        int o = o0 + j;
        float r = acc[j] * sc[o] + bi[o];
        if (RELU) r = fmaxf(r, 0.f);
        out[((size_t)b * 32 + o) * SPAT + spos + pos] = r;
    }
}

// =====================================================================
// Gram partials of a1: G[m][m'] and S[m] per 256-pos chunk (determinism)
// grid: (128, 1, B), block 256
// =====================================================================
__global__ __launch_bounds__(256) void k_gram(
    const float* __restrict__ a, float* __restrict__ partial)
{
    __shared__ float lds[32 * 257];
    int blk = blockIdx.x, b = blockIdx.z;
    const float* ap = a + (size_t)b * 32 * SPAT + blk * 256;
    for (int i = threadIdx.x; i < 32 * 64; i += 256) {
        int m = i >> 6, p4 = (i & 63) * 4;
        float4 v = *(const float4*)(ap + (size_t)m * SPAT + p4);
        lds[m * 257 + p4 + 0] = v.x; lds[m * 257 + p4 + 1] = v.y;
        lds[m * 257 + p4 + 2] = v.z; lds[m * 257 + p4 + 3] = v.w;
    }
    __syncthreads();
    float* outp = partial + (size_t)(b * 128 + blk) * 1056;
#pragma unroll
    for (int it = 0; it < 4; ++it) {
        int pid = threadIdx.x + it * 256;
        const float* pa = &lds[(pid >> 5) * 257];
        const float* pb = &lds[(pid & 31) * 257];
        float acc = 0.f;
#pragma unroll 8
        for (int p = 0; p < 256; ++p) acc = fmaf(pa[p], pb[p], acc);
        outp[pid] = acc;
    }
    if (threadIdx.x < 32) {
        const float* pa = &lds[threadIdx.x * 257];
        float scc = 0.f;
#pragma unroll 8
        for (int p = 0; p < 256; ++p) scc += pa[p];
        outp[1024 + threadIdx.x] = scc;
    }
}

// =====================================================================
// GN stats from Gram: stats[bg] = {mu, inv}
// =====================================================================
__global__ __launch_bounds__(512) void k_stats(
    const float* __restrict__ partial, const float* __restrict__ w4,
    const float* __restrict__ b4, float* __restrict__ stats)
{
    __shared__ float G[2 * 1056];
    __shared__ float sred[432], ssred[432];
    for (int e = threadIdx.x; e < 2 * 1056; e += 512) {
        int b = e / 1056, pid = e % 1056;
        float acc = 0.f;
#pragma unroll 8
        for (int blk = 0; blk < 128; ++blk)
            acc += partial[(size_t)(b * 128 + blk) * 1056 + pid];
        G[e] = acc;
    }
    __syncthreads();
    if (threadIdx.x < 432) {
        int t = threadIdx.x;
        int b = t / 216, r = t % 216, g = r / 27, k = r % 27;
        const float* wk = w4 + (g * 27 + k) * 32;
        float wreg[32];
#pragma unroll
        for (int m = 0; m < 32; ++m) wreg[m] = wk[m];
        const float* Gb = &G[b * 1056];
        const float* Sb = &G[b * 1056 + 1024];
        float sk = 0.f, ssk = 0.f;
#pragma unroll
        for (int m = 0; m < 32; ++m) {
            sk = fmaf(wreg[m], Sb[m], sk);
            float dot = 0.f;
#pragma unroll
            for (int mm = 0; mm < 32; ++mm)
                dot = fmaf(wreg[mm], Gb[m * 32 + mm], dot);
            ssk = fmaf(wreg[m], dot, ssk);
        }
        float bb = b4[g * 27 + k];
        float NN = (float)SPAT;
        ssk += 2.f * bb * sk + NN * bb * bb;
        sk  += NN * bb;
        sred[t] = sk; ssred[t] = ssk;
    }
    __syncthreads();
    if (threadIdx.x < 16) {
        int bg = threadIdx.x;
        float s = 0.f, ss = 0.f;
        for (int k = 0; k < 27; ++k) { s += sred[bg * 27 + k]; ss += ssred[bg * 27 + k]; }
        float N27 = 27.f * (float)SPAT;
        float mu = s / N27;
        float var = ss / N27 - mu * mu;
        stats[bg * 2 + 0] = mu;
        stats[bg * 2 + 1] = rsqrtf(var + GN_EPS);
    }
}

// =====================================================================
// cv4 (32 -> 216) + bias + GroupNorm affine, LDS tile: a1 read ONCE.
// Block 256 = 4 waves; wave w computes rows [w*54, w*54+54).
// Writes NORMALIZED wn. grid: (SPAT/64, 1, B)
// =====================================================================
__global__ __launch_bounds__(256) void k_wk(
    const float* __restrict__ a, const float* __restrict__ w4,
    const float* __restrict__ b4, const float* __restrict__ stats,
    const float* __restrict__ gn_g, const float* __restrict__ gn_b,
    float* __restrict__ wn)
{
    __shared__ float lds[32 * 64];
    int spos = blockIdx.x * 64, b = blockIdx.z;
    const float* ip = a + (size_t)b * 32 * SPAT + spos;
    for (int i = threadIdx.x; i < 32 * 16; i += 256) {
        int c = i >> 4, p4 = (i & 15) << 2;
        *(float4*)&lds[c * 64 + p4] = *(const float4*)(ip + (size_t)c * SPAT + p4);
    }
    __syncthreads();
    int pos = threadIdx.x & 63, wv = threadIdx.x >> 6;
    int o0 = wv * 54;
    float acc[54];
#pragma unroll
    for (int j = 0; j < 54; ++j) acc[j] = 0.f;
#pragma unroll 2
    for (int c = 0; c < 32; ++c) {
        float v = lds[c * 64 + pos];
#pragma unroll
        for (int j = 0; j < 54; ++j)
            acc[j] = fmaf(v, w4[(o0 + j) * 32 + c], acc[j]);
    }
#pragma unroll
    for (int j = 0; j < 54; ++j) {
        int o = o0 + j;
        int g = o / 27;
        float mu  = stats[(b * 8 + g) * 2 + 0];
        float inv = stats[(b * 8 + g) * 2 + 1];
        float A = gn_g[o] * inv;
        float B = fmaf(b4[o] - mu, A, gn_b[o]);   // (bias - mu)*A + gn_b
        wn[((size_t)b * 216 + o) * SPAT + spos + pos] = fmaf(acc[j], A, B);
    }
}

// =====================================================================
// SKA apply: read normalized wn (streamed) + x, BN + residual -> y
// grid: (SPAT/1024, 8 groups, B), block 256, float4 quads. 8 lanes/row.
// =====================================================================
__global__ __launch_bounds__(256) void k_ska(
    const float* __restrict__ x, const float* __restrict__ wn,
    const float* __restrict__ bn_s, const float* __restrict__ bn_b,
    float* __restrict__ y)
{
    int q = blockIdx.x * 256 + threadIdx.x;
    int s = q * 4;
    int g = blockIdx.y, b = blockIdx.z;
    int d = s >> 10, h = (s >> 5) & 31, w0 = s & 31;
    int lane = threadIdx.x & 63;
    int xl_src = (lane & 56) | ((lane + 7) & 7);
    int xr_src = (lane & 56) | ((lane + 1) & 7);
    const float* xg = x + ((size_t)(b * 64 + g * 8)) * SPAT;
    const float* wp = wn + ((size_t)(b * 216 + g * 27)) * SPAT + s;

    float4 acc[8];
    float4 xc[8];
#pragma unroll
    for (int c = 0; c < 8; ++c) acc[c] = {0.f, 0.f, 0.f, 0.f};

#pragma unroll
    for (int kd = 0; kd < 3; ++kd) {
        int zd = (d + kd + 31) & 31;
#pragma unroll
        for (int kh = 0; kh < 3; ++kh) {
            int zh = (h + kh + 31) & 31;
            int kbase = (kd * 3 + kh) * 3;
            float4 wt[3];
#pragma unroll
            for (int kw = 0; kw < 3; ++kw)
                wt[kw] = *(const float4*)(wp + (size_t)(kbase + kw) * SPAT);
            int rowoff = zd * 1024 + zh * 32;
            bool center = (kd == 1) && (kh == 1);
#pragma unroll
            for (int c = 0; c < 8; ++c) {
                float4 m = *(const float4*)(xg + (size_t)c * SPAT + rowoff + w0);
                if (center) xc[c] = m;
                float xl = __shfl(m.w, xl_src, 64);
                float xr = __shfl(m.x, xr_src, 64);
                float win[6] = {xl, m.x, m.y, m.z, m.w, xr};
#pragma unroll
                for (int kw = 0; kw < 3; ++kw) {
                    acc[c].x = fmaf(win[0 + kw], wt[kw].x, acc[c].x);
                    acc[c].y = fmaf(win[1 + kw], wt[kw].y, acc[c].y);
                    acc[c].z = fmaf(win[2 + kw], wt[kw].z, acc[c].z);
                    acc[c].w = fmaf(win[3 + kw], wt[kw].w, acc[c].w);
                }
            }
        }
    }
#pragma unroll
    for (int c = 0; c < 8; ++c) {
        int ch = g * 8 + c;
        float bs = bn_s[ch], bb = bn_b[ch];
        float4 r;
        r.x = acc[c].x * bs + bb + xc[c].x;
        r.y = acc[c].y * bs + bb + xc[c].y;
        r.z = acc[c].z * bs + bb + xc[c].z;
        r.w = acc[c].w * bs + bb + xc[c].w;
        *(float4*)(y + ((size_t)(b * 64 + ch)) * SPAT + s) = r;
    }
}

// =====================================================================
// Fused FFN: pw1 + BN + ReLU + pw2 + BN + residual, all through LDS.
// Block 256 = 4 waves; tile 64 positions. f1 NEVER hits global memory.
// grid: (SPAT/64, 1, B)
// =====================================================================
__global__ __launch_bounds__(256) void k_ffn(
    const float* __restrict__ yin,
    const float* __restrict__ pw1_w, const float* __restrict__ pw1_s,
    const float* __restrict__ pw1_b,
    const float* __restrict__ pw2_w, const float* __restrict__ pw2_s,
    const float* __restrict__ pw2_b,
    float* __restrict__ out)
{
    __shared__ float ylds[64 * 64];   // 16 KB
    __shared__ float flds[64 * 64];   // 16 KB (one 64-ch f-chunk)
    int spos = blockIdx.x * 64, b = blockIdx.z;
    const float* ip = yin + (size_t)b * 64 * SPAT + spos;
    for (int i = threadIdx.x; i < 64 * 16; i += 256) {
        int c = i >> 4, p4 = (i & 15) << 2;
        *(float4*)&ylds[c * 64 + p4] = *(const float4*)(ip + (size_t)c * SPAT + p4);
    }
    __syncthreads();
    int pos = threadIdx.x & 63, wv = threadIdx.x >> 6;
    float outacc[16];
#pragma unroll
    for (int j = 0; j < 16; ++j) outacc[j] = 0.f;

#pragma unroll
    for (int ph = 0; ph < 2; ++ph) {
        // ---- pw1: wave wv computes f channels [ph*64 + wv*16, +16) ----
        int f0 = ph * 64 + wv * 16;
        float fa[16];
#pragma unroll
        for (int j = 0; j < 16; ++j) fa[j] = 0.f;
#pragma unroll 4
        for (int c = 0; c < 64; ++c) {
            float v = ylds[c * 64 + pos];
#pragma unroll
            for (int j = 0; j < 16; ++j)
                fa[j] = fmaf(v, pw1_w[(f0 + j) * 64 + c], fa[j]);
        }
#pragma unroll
        for (int j = 0; j < 16; ++j) {
            float r = fa[j] * pw1_s[f0 + j] + pw1_b[f0 + j];
            flds[(wv * 16 + j) * 64 + pos] = fmaxf(r, 0.f);
        }
        __syncthreads();
        // ---- pw2 partial: wave wv accumulates outputs [wv*16, +16) ----
        int fo = ph * 64;
#pragma unroll 4
        for (int fc = 0; fc < 64; ++fc) {
            float fv = flds[fc * 64 + pos];
#pragma unroll
            for (int j = 0; j < 16; ++j)
                outacc[j] = fmaf(fv, pw2_w[(wv * 16 + j) * 128 + fo + fc], outacc[j]);
        }
        __syncthreads();
    }
    int o0 = wv * 16;
#pragma unroll
    for (int j = 0; j < 16; ++j) {
        int o = o0 + j;
        float r = outacc[j] * pw2_s[o] + pw2_b[o] + ylds[o * 64 + pos];
        out[((size_t)b * 64 + o) * SPAT + spos + pos] = r;
    }
}

// =====================================================================
// depthwise 5x5x5, zero pad 2, + affine, LDS-tiled (2 output planes)
// =====================================================================
__global__ __launch_bounds__(256, 4) void k_dw5(
    const float* __restrict__ in, const float* __restrict__ w2,
    const float* __restrict__ s2, const float* __restrict__ b2,
    float* __restrict__ out)
{
    __shared__ float lds[6 * 36 * 40];           // 34,560 B
    int tid = threadIdx.x;
    int d0 = blockIdx.x * 2;
    int c = blockIdx.y, b = blockIdx.z;
    const float* ip = in + ((size_t)(b * 32 + c)) * SPAT;

    float4 z = {0.f, 0.f, 0.f, 0.f};
    for (int i = tid; i < 6 * 36 * 40 / 4; i += 256)
        ((float4*)lds)[i] = z;
    __syncthreads();
    for (int i = tid; i < 6 * 256; i += 256) {
        int p = i >> 8, rem = i & 255;
        int r = rem >> 3, c4 = (rem & 7) * 4;
        int d = d0 - 2 + p;
        if (d >= 0 && d < 32) {
            float4 v = *(const float4*)(ip + d * 1024 + r * 32 + c4);
            *(float4*)&lds[p * 1440 + (r + 2) * 40 + (c4 + 4)] = v;
        }
    }
    __syncthreads();

    float scl = s2[c], shf = b2[c];
    const float* wt = w2 + c * 125;
#pragma unroll
    for (int k = 0; k < 2; ++k) {
        int j = tid + k * 256;
        int pd = j >> 8, rem = j & 255;
        int hr = rem >> 3, w4i = (rem & 7) * 4;
        float4 acc = {0.f, 0.f, 0.f, 0.f};
#pragma unroll
        for (int kd = 0; kd < 5; ++kd) {
            const float* pl = &lds[(pd + kd) * 1440];
#pragma unroll
            for (int kh = 0; kh < 5; ++kh) {
                const float* row = pl + (hr + kh) * 40 + w4i;
                float4 r0 = *(const float4*)(row);
                float4 r1 = *(const float4*)(row + 4);
                float4 r2 = *(const float4*)(row + 8);
                float win[12] = {r0.x, r0.y, r0.z, r0.w,
                                 r1.x, r1.y, r1.z, r1.w,
                                 r2.x, r2.y, r2.z, r2.w};
#pragma unroll
                for (int kw = 0; kw < 5; ++kw) {
                    float wv = wt[kd * 25 + kh * 5 + kw];
                    acc.x = fmaf(wv, win[2 + 0 + kw], acc.x);
                    acc.y = fmaf(wv, win[2 + 1 + kw], acc.y);
                    acc.z = fmaf(wv, win[2 + 2 + kw], acc.z);
                    acc.w = fmaf(wv, win[2 + 3 + kw], acc.w);
                }
            }
        }
        acc.x = acc.x * scl + shf; acc.y = acc.y * scl + shf;
        acc.z = acc.z * scl + shf; acc.w = acc.w * scl + shf;
        *(float4*)(out + ((size_t)(b * 32 + c)) * SPAT
                   + (d0 + pd) * 1024 + hr * 32 + w4i) = acc;
    }
}

extern "C" void kernel_launch(void* const* d_in, const int* in_sizes, int n_in,
                              void* d_out, int out_size, void* d_ws, size_t ws_size,
                              hipStream_t stream)
{
    const float* x     = (const float*)d_in[0];
    const float* w1    = (const float*)d_in[1];
    const float* s1    = (const float*)d_in[2];
    const float* b1    = (const float*)d_in[3];
    const float* w2    = (const float*)d_in[4];
    const float* s2    = (const float*)d_in[5];
    const float* b2    = (const float*)d_in[6];
    const float* w3    = (const float*)d_in[7];
    const float* s3    = (const float*)d_in[8];
    const float* b3    = (const float*)d_in[9];
    const float* w4    = (const float*)d_in[10];
    const float* b4    = (const float*)d_in[11];
    const float* gn_g  = (const float*)d_in[12];
    const float* gn_b  = (const float*)d_in[13];
    const float* bn_s  = (const float*)d_in[14];
    const float* bn_b  = (const float*)d_in[15];
    const float* pw1_w = (const float*)d_in[16];
    const float* pw1_s = (const float*)d_in[17];
    const float* pw1_b = (const float*)d_in[18];
    const float* pw2_w = (const float*)d_in[19];
    const float* pw2_s = (const float*)d_in[20];
    const float* pw2_b = (const float*)d_in[21];

    // Workspace 73.4 MB with lifetime-overlapped regions:
    //   [0,16MB): a1 | a2, later y (a1/a2 dead after k_wk / k_cv3)
    //   [16,72.6MB): part (gram), later wn (part dead after k_stats)
    //   [72.6MB +]: stats (32 floats)
    float* ws    = (float*)d_ws;
    float* a1    = ws;                                   // 8 MB
    float* a2    = a1 + (size_t)BATCH * 32 * SPAT;       // 8 MB
    float* yb    = ws;                                   // 16 MB (over a1,a2)
    float* wn    = ws + (size_t)BATCH * 64 * SPAT;       // 56.6 MB
    float* part  = wn;                                   // 1.08 MB (over wn)
    float* stats = wn + (size_t)BATCH * 216 * SPAT;      // 32 floats

    dim3 blk(256);
    // cv1 + BN + ReLU : 64 -> 32 (LDS tile, x read once)
    k_c1t<64, true><<<dim3(SPAT / 64, 1, BATCH), blk, 0, stream>>>(
        x, w1, s1, b1, a1);
    // dw 5^3 + BN
    k_dw5<<<dim3(16, 32, BATCH), blk, 0, stream>>>(a1, w2, s2, b2, a2);
    // cv3 + BN + ReLU : 32 -> 32
    k_c1t<32, true><<<dim3(SPAT / 64, 1, BATCH), blk, 0, stream>>>(
        a2, w3, s3, b3, a1);
    // Gram partials + GN stats (linearity trick)
    k_gram<<<dim3(128, 1, BATCH), blk, 0, stream>>>(a1, part);
    k_stats<<<dim3(1), dim3(512), 0, stream>>>(part, w4, b4, stats);
    // cv4 + bias + GN affine -> normalized wn (a1 read once)
    k_wk<<<dim3(SPAT / 64, 1, BATCH), blk, 0, stream>>>(
        a1, w4, b4, stats, gn_g, gn_b, wn);
    // SKA apply + BN + residual -> y
    k_ska<<<dim3(SPAT / 1024, 8, BATCH), blk, 0, stream>>>(
        x, wn, bn_s, bn_b, yb);
    // FFN fused: pw1+BN+ReLU+pw2+BN+residual -> out (f1 never in HBM)
    k_ffn<<<dim3(SPAT / 64, 1, BATCH), blk, 0, stream>>>(
        yb, pw1_w, pw1_s, pw1_b, pw2_w, pw2_s, pw2_b, (float*)d_out);
}

// Round 5
// 281.281 us; speedup vs baseline: 1.9257x; 1.9257x over previous
//
#include <hip/hip_runtime.h>

#define SPAT 32768   // 32*32*32
#define BATCH 2
#define GN_EPS 1e-5f

__device__ __forceinline__ void fma2(float2& a, const float2& v, float w) {
    a.x = fmaf(v.x, w, a.x); a.y = fmaf(v.y, w, a.y);
}

// =====================================================================
// 1x1x1 conv: float2 spatial x NO output channels. o0 is BLOCK-uniform
// (blockIdx.y) so weight reads compile to s_load.
// grid: (SPAT/512, Cout/NO, B), block 256
// =====================================================================
template <int CIN, int NO, bool RELU, bool AFF>
__global__ __launch_bounds__(256) void k_c1(
    const float* __restrict__ in, const float* __restrict__ w,
    const float* __restrict__ sc, const float* __restrict__ bi,
    float* __restrict__ out, int Cout)
{
    int q = blockIdx.x * 256 + threadIdx.x;      // float2 index within batch
    int o0 = blockIdx.y * NO, b = blockIdx.z;
    const float2* ip = (const float2*)(in + (size_t)b * CIN * SPAT) + q;
    float2 acc[NO];
#pragma unroll
    for (int i = 0; i < NO; ++i) acc[i] = {0.f, 0.f};
#pragma unroll 4
    for (int c = 0; c < CIN; ++c) {
        float2 v = ip[(size_t)c * (SPAT / 2)];
#pragma unroll
        for (int i = 0; i < NO; ++i)
            fma2(acc[i], v, w[(o0 + i) * CIN + c]);
    }
    float2* op = (float2*)(out + (size_t)b * Cout * SPAT) + q;
#pragma unroll
    for (int i = 0; i < NO; ++i) {
        int o = o0 + i;
        float scale = AFF ? sc[o] : 1.f;
        float shift = bi[o];
        float2 r = acc[i];
        r.x = r.x * scale + shift; r.y = r.y * scale + shift;
        if (RELU) { r.x = fmaxf(r.x, 0.f); r.y = fmaxf(r.y, 0.f); }
        op[(size_t)o * (SPAT / 2)] = r;
    }
}

// =====================================================================
// Gram partials of a1: G[m][m'] and S[m] per 256-pos chunk (determinism)
// grid: (128, 1, B), block 256
// =====================================================================
__global__ __launch_bounds__(256) void k_gram(
    const float* __restrict__ a, float* __restrict__ partial)
{
    __shared__ float lds[32 * 257];
    int blk = blockIdx.x, b = blockIdx.z;
    const float* ap = a + (size_t)b * 32 * SPAT + blk * 256;
    for (int i = threadIdx.x; i < 32 * 64; i += 256) {
        int m = i >> 6, p4 = (i & 63) * 4;
        float4 v = *(const float4*)(ap + (size_t)m * SPAT + p4);
        lds[m * 257 + p4 + 0] = v.x; lds[m * 257 + p4 + 1] = v.y;
        lds[m * 257 + p4 + 2] = v.z; lds[m * 257 + p4 + 3] = v.w;
    }
    __syncthreads();
    float* outp = partial + (size_t)(b * 128 + blk) * 1056;
#pragma unroll
    for (int it = 0; it < 4; ++it) {
        int pid = threadIdx.x + it * 256;
        const float* pa = &lds[(pid >> 5) * 257];
        const float* pb = &lds[(pid & 31) * 257];
        float acc = 0.f;
#pragma unroll 8
        for (int p = 0; p < 256; ++p) acc = fmaf(pa[p], pb[p], acc);
        outp[pid] = acc;
    }
    if (threadIdx.x < 32) {
        const float* pa = &lds[threadIdx.x * 257];
        float scc = 0.f;
#pragma unroll 8
        for (int p = 0; p < 256; ++p) scc += pa[p];
        outp[1024 + threadIdx.x] = scc;
    }
}

// =====================================================================
// GN stats from Gram: stats[bg] = {mu, inv}
// =====================================================================
__global__ __launch_bounds__(512) void k_stats(
    const float* __restrict__ partial, const float* __restrict__ w4,
    const float* __restrict__ b4, float* __restrict__ stats)
{
    __shared__ float G[2 * 1056];
    __shared__ float sred[432], ssred[432];
    for (int e = threadIdx.x; e < 2 * 1056; e += 512) {
        int b = e / 1056, pid = e % 1056;
        float acc = 0.f;
#pragma unroll 8
        for (int blk = 0; blk < 128; ++blk)
            acc += partial[(size_t)(b * 128 + blk) * 1056 + pid];
        G[e] = acc;
    }
    __syncthreads();
    if (threadIdx.x < 432) {
        int t = threadIdx.x;
        int b = t / 216, r = t % 216, g = r / 27, k = r % 27;
        const float* wk = w4 + (g * 27 + k) * 32;
        float wreg[32];
#pragma unroll
        for (int m = 0; m < 32; ++m) wreg[m] = wk[m];
        const float* Gb = &G[b * 1056];
        const float* Sb = &G[b * 1056 + 1024];
        float sk = 0.f, ssk = 0.f;
#pragma unroll
        for (int m = 0; m < 32; ++m) {
            sk = fmaf(wreg[m], Sb[m], sk);
            float dot = 0.f;
#pragma unroll
            for (int mm = 0; mm < 32; ++mm)
                dot = fmaf(wreg[mm], Gb[m * 32 + mm], dot);
            ssk = fmaf(wreg[m], dot, ssk);
        }
        float bb = b4[g * 27 + k];
        float NN = (float)SPAT;
        ssk += 2.f * bb * sk + NN * bb * bb;
        sk  += NN * bb;
        sred[t] = sk; ssred[t] = ssk;
    }
    __syncthreads();
    if (threadIdx.x < 16) {
        int bg = threadIdx.x;
        float s = 0.f, ss = 0.f;
        for (int k = 0; k < 27; ++k) { s += sred[bg * 27 + k]; ss += ssred[bg * 27 + k]; }
        float N27 = 27.f * (float)SPAT;
        float mu = s / N27;
        float var = ss / N27 - mu * mu;
        stats[bg * 2 + 0] = mu;
        stats[bg * 2 + 1] = rsqrtf(var + GN_EPS);
    }
}

// =====================================================================
// SKA: group-major, float4 quads, shuffle wrap, in-register GN normalize.
// grid: (SPAT/1024, 8 groups, B), block 256. (round-0-proven structure)
// =====================================================================
__global__ __launch_bounds__(256) void k_ska(
    const float* __restrict__ x, const float* __restrict__ wk,
    const float* __restrict__ stats,
    const float* __restrict__ gn_g, const float* __restrict__ gn_b,
    const float* __restrict__ bn_s, const float* __restrict__ bn_b,
    float* __restrict__ y)
{
    int q = blockIdx.x * 256 + threadIdx.x;
    int s = q * 4;
    int g = blockIdx.y, b = blockIdx.z;
    int bg = b * 8 + g;
    float mu  = stats[bg * 2 + 0];
    float inv = stats[bg * 2 + 1];
    int d = s >> 10, h = (s >> 5) & 31, w0 = s & 31;
    int lane = threadIdx.x & 63;
    int xl_src = (lane & 56) | ((lane + 7) & 7);   // left neighbor in 8-lane row group
    int xr_src = (lane & 56) | ((lane + 1) & 7);   // right neighbor
    const float* xg = x + ((size_t)(b * 64 + g * 8)) * SPAT;
    const float* wp = wk + ((size_t)(b * 216 + g * 27)) * SPAT + s;

    float4 acc[8];
    float4 xc[8];
#pragma unroll
    for (int c = 0; c < 8; ++c) acc[c] = {0.f, 0.f, 0.f, 0.f};

#pragma unroll
    for (int kd = 0; kd < 3; ++kd) {
        int zd = (d + kd + 31) & 31;
#pragma unroll
        for (int kh = 0; kh < 3; ++kh) {
            int zh = (h + kh + 31) & 31;
            int kbase = (kd * 3 + kh) * 3;
            float wn[3][4];
#pragma unroll
            for (int kw = 0; kw < 3; ++kw) {
                int kk = kbase + kw;
                float4 wq = *(const float4*)(wp + (size_t)kk * SPAT);
                float A = gn_g[g * 27 + kk] * inv;
                float B = gn_b[g * 27 + kk] - mu * A;
                wn[kw][0] = wq.x * A + B;
                wn[kw][1] = wq.y * A + B;
                wn[kw][2] = wq.z * A + B;
                wn[kw][3] = wq.w * A + B;
            }
            int rowoff = zd * 1024 + zh * 32;
            bool center = (kd == 1) && (kh == 1);
#pragma unroll
            for (int c = 0; c < 8; ++c) {
                float4 m = *(const float4*)(xg + (size_t)c * SPAT + rowoff + w0);
                if (center) xc[c] = m;
                float xl = __shfl(m.w, xl_src, 64);
                float xr = __shfl(m.x, xr_src, 64);
                float win[6] = {xl, m.x, m.y, m.z, m.w, xr};
#pragma unroll
                for (int kw = 0; kw < 3; ++kw) {
                    acc[c].x = fmaf(win[0 + kw], wn[kw][0], acc[c].x);
                    acc[c].y = fmaf(win[1 + kw], wn[kw][1], acc[c].y);
                    acc[c].z = fmaf(win[2 + kw], wn[kw][2], acc[c].z);
                    acc[c].w = fmaf(win[3 + kw], wn[kw][3], acc[c].w);
                }
            }
        }
    }
#pragma unroll
    for (int c = 0; c < 8; ++c) {
        int ch = g * 8 + c;
        float bs = bn_s[ch], bb = bn_b[ch];
        float4 r;
        r.x = acc[c].x * bs + bb + xc[c].x;
        r.y = acc[c].y * bs + bb + xc[c].y;
        r.z = acc[c].z * bs + bb + xc[c].z;
        r.w = acc[c].w * bs + bb + xc[c].w;
        *(float4*)(y + ((size_t)(b * 64 + ch)) * SPAT + s) = r;
    }
}

// =====================================================================
// depthwise 5x5x5, zero pad 2, + affine, LDS-tiled (2 output planes)
// =====================================================================
__global__ __launch_bounds__(256, 4) void k_dw5(
    const float* __restrict__ in, const float* __restrict__ w2,
    const float* __restrict__ s2, const float* __restrict__ b2,
    float* __restrict__ out)
{
    __shared__ float lds[6 * 36 * 40];           // 34,560 B
    int tid = threadIdx.x;
    int d0 = blockIdx.x * 2;
    int c = blockIdx.y, b = blockIdx.z;
    const float* ip = in + ((size_t)(b * 32 + c)) * SPAT;

    float4 z = {0.f, 0.f, 0.f, 0.f};
    for (int i = tid; i < 6 * 36 * 40 / 4; i += 256)
        ((float4*)lds)[i] = z;
    __syncthreads();
    for (int i = tid; i < 6 * 256; i += 256) {
        int p = i >> 8, rem = i & 255;
        int r = rem >> 3, c4 = (rem & 7) * 4;
        int d = d0 - 2 + p;
        if (d >= 0 && d < 32) {
            float4 v = *(const float4*)(ip + d * 1024 + r * 32 + c4);
            *(float4*)&lds[p * 1440 + (r + 2) * 40 + (c4 + 4)] = v;
        }
    }
    __syncthreads();

    float scl = s2[c], shf = b2[c];
    const float* wt = w2 + c * 125;
#pragma unroll
    for (int k = 0; k < 2; ++k) {
        int j = tid + k * 256;
        int pd = j >> 8, rem = j & 255;
        int hr = rem >> 3, w4i = (rem & 7) * 4;
        float4 acc = {0.f, 0.f, 0.f, 0.f};
#pragma unroll
        for (int kd = 0; kd < 5; ++kd) {
            const float* pl = &lds[(pd + kd) * 1440];
#pragma unroll
            for (int kh = 0; kh < 5; ++kh) {
                const float* row = pl + (hr + kh) * 40 + w4i;
                float4 r0 = *(const float4*)(row);
                float4 r1 = *(const float4*)(row + 4);
                float4 r2 = *(const float4*)(row + 8);
                float win[12] = {r0.x, r0.y, r0.z, r0.w,
                                 r1.x, r1.y, r1.z, r1.w,
                                 r2.x, r2.y, r2.z, r2.w};
#pragma unroll
                for (int kw = 0; kw < 5; ++kw) {
                    float wv = wt[kd * 25 + kh * 5 + kw];
                    acc.x = fmaf(wv, win[2 + 0 + kw], acc.x);
                    acc.y = fmaf(wv, win[2 + 1 + kw], acc.y);
                    acc.z = fmaf(wv, win[2 + 2 + kw], acc.z);
                    acc.w = fmaf(wv, win[2 + 3 + kw], acc.w);
                }
            }
        }
        acc.x = acc.x * scl + shf; acc.y = acc.y * scl + shf;
        acc.z = acc.z * scl + shf; acc.w = acc.w * scl + shf;
        *(float4*)(out + ((size_t)(b * 32 + c)) * SPAT
                   + (d0 + pd) * 1024 + hr * 32 + w4i) = acc;
    }
}

// =====================================================================
// pw2 (128->64) + affine + residual, float2, NO outs, block-uniform o0
// =====================================================================
template <int NO>
__global__ __launch_bounds__(256) void k_pw2_out(
    const float* __restrict__ f1, const float* __restrict__ w,
    const float* __restrict__ sc, const float* __restrict__ bi,
    const float* __restrict__ yres, float* __restrict__ out)
{
    int q = blockIdx.x * 256 + threadIdx.x;
    int o0 = blockIdx.y * NO, b = blockIdx.z;
    const float2* ip = (const float2*)(f1 + (size_t)b * 128 * SPAT) + q;
    float2 acc[NO];
#pragma unroll
    for (int i = 0; i < NO; ++i) acc[i] = {0.f, 0.f};
#pragma unroll 4
    for (int c = 0; c < 128; ++c) {
        float2 v = ip[(size_t)c * (SPAT / 2)];
#pragma unroll
        for (int i = 0; i < NO; ++i)
            fma2(acc[i], v, w[(o0 + i) * 128 + c]);
    }
    const float2* yp = (const float2*)(yres + (size_t)b * 64 * SPAT) + q;
    float2* op = (float2*)(out + (size_t)b * 64 * SPAT) + q;
#pragma unroll
    for (int i = 0; i < NO; ++i) {
        int o = o0 + i;
        float scale = sc[o], shift = bi[o];
        float2 yv = yp[(size_t)o * (SPAT / 2)];
        float2 r = acc[i];
        r.x = r.x * scale + shift + yv.x;
        r.y = r.y * scale + shift + yv.y;
        op[(size_t)o * (SPAT / 2)] = r;
    }
}

extern "C" void kernel_launch(void* const* d_in, const int* in_sizes, int n_in,
                              void* d_out, int out_size, void* d_ws, size_t ws_size,
                              hipStream_t stream)
{
    const float* x     = (const float*)d_in[0];
    const float* w1    = (const float*)d_in[1];
    const float* s1    = (const float*)d_in[2];
    const float* b1    = (const float*)d_in[3];
    const float* w2    = (const float*)d_in[4];
    const float* s2    = (const float*)d_in[5];
    const float* b2    = (const float*)d_in[6];
    const float* w3    = (const float*)d_in[7];
    const float* s3    = (const float*)d_in[8];
    const float* b3    = (const float*)d_in[9];
    const float* w4    = (const float*)d_in[10];
    const float* b4    = (const float*)d_in[11];
    const float* gn_g  = (const float*)d_in[12];
    const float* gn_b  = (const float*)d_in[13];
    const float* bn_s  = (const float*)d_in[14];
    const float* bn_b  = (const float*)d_in[15];
    const float* pw1_w = (const float*)d_in[16];
    const float* pw1_s = (const float*)d_in[17];
    const float* pw1_b = (const float*)d_in[18];
    const float* pw2_w = (const float*)d_in[19];
    const float* pw2_s = (const float*)d_in[20];
    const float* pw2_b = (const float*)d_in[21];

    // Workspace ~73.5 MB, lifetime-overlapped:
    //   [0,16MB):  a1 | a2 (LKP), later y (SKA/FFN)
    //   [16MB..):  wk (2*216*S = 56.6MB) during cv4..ska, then f1 (32MB) for FFN
    //   tail: gram partials (1.08MB) + stats (32 floats)
    float* ws    = (float*)d_ws;
    float* a1    = ws;                                   // 8 MB
    float* a2    = a1 + (size_t)BATCH * 32 * SPAT;       // 8 MB
    float* yb    = ws;                                   // 16 MB (over a1,a2)
    float* wkb   = ws + (size_t)BATCH * 64 * SPAT;       // 56.6 MB
    float* f1    = wkb;                                  // 32 MB (over wk, after ska)
    float* part  = wkb + (size_t)BATCH * 216 * SPAT;     // 1.08 MB
    float* stats = part + (size_t)256 * 1056;            // 32 floats

    dim3 blk(256);
    // cv1 + BN + ReLU : 64 -> 32  (float2, 8 out/thread, 512 blocks)
    k_c1<64, 8, true, true><<<dim3(SPAT / 512, 4, BATCH), blk, 0, stream>>>(
        x, w1, s1, b1, a1, 32);
    // dw 5^3 + BN (LDS-tiled, 1024 blocks)
    k_dw5<<<dim3(16, 32, BATCH), blk, 0, stream>>>(a1, w2, s2, b2, a2);
    // cv3 + BN + ReLU : 32 -> 32
    k_c1<32, 8, true, true><<<dim3(SPAT / 512, 4, BATCH), blk, 0, stream>>>(
        a2, w3, s3, b3, a1, 32);
    // GN stats via Gram linearity (reads a1 once)
    k_gram<<<dim3(128, 1, BATCH), blk, 0, stream>>>(a1, part);
    k_stats<<<dim3(1), dim3(512), 0, stream>>>(part, w4, b4, stats);
    // cv4 + bias : 32 -> 216 raw wk  (float2, 8 out/thread, 3456 blocks)
    k_c1<32, 8, false, false><<<dim3(SPAT / 512, 27, BATCH), blk, 0, stream>>>(
        a1, w4, nullptr, b4, wkb, 216);
    // SKA + in-register GN + BN + residual -> y
    k_ska<<<dim3(SPAT / 1024, 8, BATCH), blk, 0, stream>>>(
        x, wkb, stats, gn_g, gn_b, bn_s, bn_b, yb);
    // pw1 + BN + ReLU : 64 -> 128  (float2, 8 out/thread, 2048 blocks)
    k_c1<64, 8, true, true><<<dim3(SPAT / 512, 16, BATCH), blk, 0, stream>>>(
        yb, pw1_w, pw1_s, pw1_b, f1, 128);
    // pw2 + BN + residual -> out  (float2, 8 out/thread, 1024 blocks)
    k_pw2_out<8><<<dim3(SPAT / 512, 8, BATCH), blk, 0, stream>>>(
        f1, pw2_w, pw2_s, pw2_b, yb, (float*)d_out);
}